// Round 2
// baseline (169.372 us; speedup 1.0000x reference)
//
#include <hip/hip_runtime.h>
#include <math.h>

// SpectralConv2d: out = idht2( mix( dht2(x)[:, :, :32, :32], W ) ) / S^2
// x:  [32][64][128][128] f32   weights1: [64][64][32][32] f32
// out:[32][64][128][128] f32
//
// M is the recursive pseudo-Hartley operator (NOT plain cas(2pi kn/N)):
//   M[k,n] = prod over levels (size Nj = 128,64,...,2):
//     if bit_j(n): (k_j < Nj/2 ? +1 : -1) * cas(2*pi*(k_j mod Nj/2)/Nj), else 1
//     with k_{j+1} = k_j mod (Nj/2).

#define SS   128
#define MD   32
#define NBAT 32
#define CI   64
#define CO   64

#define TWO_PI 6.2831853071795864769

// ws layout (floats):
//   M  [128][128] at 0        (M[k][n])
//   MT [128][128] at 16384    (MT[n][k] = M[k][n])
//   Xh [2048][32][32] at 32768
//   blk[2048][32][32] after Xh
static const size_t OFF_M   = 0;
static const size_t OFF_MT  = 16384;
static const size_t OFF_XH  = 32768;
static const size_t OFF_BLK = 32768 + (size_t)2048 * 1024;

__global__ void k_build(float* __restrict__ M, float* __restrict__ MT) {
    int idx = blockIdx.x * 256 + threadIdx.x;   // 16384 entries
    int k = idx >> 7, n = idx & 127;
    float prod = 1.f;
    int kk = k, nn = n;
    for (int Nj = SS; Nj > 1; Nj >>= 1) {
        int half = Nj >> 1;
        int k1 = kk & (half - 1);
        if (nn & 1) {
            double ang = (TWO_PI / (double)Nj) * (double)k1;
            float cas = (float)(cos(ang) + sin(ang));
            prod *= (kk < half) ? cas : -cas;
        }
        kk = k1;
        nn >>= 1;
    }
    M[idx] = prod;
    MT[n * 128 + k] = prod;
}

// Forward: per (b,c) block: Xh[k][l] = sum_{h,w} M[k][h]*M[l][w]*x[h][w], k,l<32
__global__ __launch_bounds__(256) void k_fwd(const float* __restrict__ x,
                                             const float* __restrict__ MT,
                                             float* __restrict__ Xh) {
    const int bc = blockIdx.x;
    const float* xp = x + (size_t)bc * (SS * SS);
    const int t = threadIdx.x;
    __shared__ float Ys[MD][SS + 1];   // Y[k][w], padded: bank = (k+w)%32

    // Phase 1: Y[k][w] = sum_h M[k][h] * x[h][w]
    // lane -> w; wave-uniform kh picks k half; M via uniform s_load of MT rows.
    const int w  = t & 127;
    const int kh = __builtin_amdgcn_readfirstlane(t >> 7);   // 0,0,1,1 per wave
    {
        float acc[16];
#pragma unroll
        for (int j = 0; j < 16; ++j) acc[j] = 0.f;
#pragma unroll 4
        for (int h = 0; h < SS; ++h) {
            float xv = xp[h * SS + w];                  // coalesced, L1 reuse x2
            const float* mrow = MT + h * 128 + kh * 16; // uniform -> s_load
#pragma unroll
            for (int j = 0; j < 16; ++j)
                acc[j] = fmaf(mrow[j], xv, acc[j]);
        }
#pragma unroll
        for (int j = 0; j < 16; ++j) Ys[kh * 16 + j][w] = acc[j];
    }
    __syncthreads();

    // Phase 2: Z[k][l] = sum_w Y[k][w] * M[l][w];  M[l][w] = MT[w*128+l]
    // lane -> k (upper 32 lanes duplicate); l-set uniform per wave (s_load).
    const int k   = t & 31;
    const int dup = (t >> 5) & 1;
    const int wid = __builtin_amdgcn_readfirstlane(t >> 6);  // 0..3
    float z[8];
#pragma unroll
    for (int j = 0; j < 8; ++j) z[j] = 0.f;
#pragma unroll 8
    for (int ww = 0; ww < SS; ++ww) {
        float yv = Ys[k][ww];                        // conflict-free: (k+ww)%32
        const float* mcol = MT + ww * 128 + wid * 8; // uniform -> s_load
#pragma unroll
        for (int j = 0; j < 8; ++j)
            z[j] = fmaf(mcol[j], yv, z[j]);
    }
    if (dup == 0) {
        float* outp = Xh + (size_t)bc * (MD * MD) + k * MD + wid * 8;
#pragma unroll
        for (int j = 0; j < 8; ++j) outp[j] = z[j];
    }
}

// Mix: blk[b][o][xy] = sum_i Xh[b][i][xy]*We[i][o][xy] + Xh[b][i][nxy]*Wo[i][o][xy]
// We = 0.5*(w[xy]+w[nxy]), Wo = 0.5*(w[xy]-w[nxy]).
// lane -> xy (all global accesses coalesced; neg-freq is an intra-line permute).
// 1024 blocks (4 blocks/CU -> 16 waves/CU) to hide L2/L3 latency; 32-bit addressing.
__global__ __launch_bounds__(256) void k_mix(const float* __restrict__ Xh,
                                             const float* __restrict__ wgt,
                                             float* __restrict__ blk) {
    const int bid = blockIdx.x;     // 1024 blocks = 4 xyc * 8 bg * 32 og
    const int xyc = bid & 3;
    const int bg  = (bid >> 2) & 7;   // 4 batches per group
    const int og  = bid >> 5;         // 2 outputs per group
    const int t   = threadIdx.x;
    const int xy  = xyc * 256 + t;
    const int xm  = xy >> 5, ym = xy & 31;
    const int nxy = ((32 - xm) & 31) * 32 + ((32 - ym) & 31);

    float acc[4][2];
#pragma unroll
    for (int bi = 0; bi < 4; ++bi)
#pragma unroll
        for (int oi = 0; oi < 2; ++oi) acc[bi][oi] = 0.f;

    const int xb0 = (bg * 4) * (CI * 1024);   // + bi*CI*1024 + i*1024
    const int wb0 = (og * 2) * 1024;          // + i*CO*1024 + oi*1024

#pragma unroll 4
    for (int i = 0; i < CI; ++i) {
        float x1[4], x1n[4];
#pragma unroll
        for (int bi = 0; bi < 4; ++bi) {
            int base = xb0 + (bi * CI + i) * 1024;
            x1[bi]  = Xh[base + xy];
            x1n[bi] = Xh[base + nxy];
        }
#pragma unroll
        for (int oi = 0; oi < 2; ++oi) {
            int wb = wb0 + (i * CO + oi) * 1024;
            float wv = wgt[wb + xy];
            float wn = wgt[wb + nxy];
            float we = 0.5f * (wv + wn);
            float wo = 0.5f * (wv - wn);
#pragma unroll
            for (int bi = 0; bi < 4; ++bi)
                acc[bi][oi] = fmaf(x1[bi], we, fmaf(x1n[bi], wo, acc[bi][oi]));
        }
    }
#pragma unroll
    for (int bi = 0; bi < 4; ++bi)
#pragma unroll
        for (int oi = 0; oi < 2; ++oi)
            blk[((bg * 4 + bi) * CO + og * 2 + oi) * 1024 + xy] = acc[bi][oi];
}

// Inverse: per (b,o) block:
//   T[r][l]   = (1/16384) * sum_{h<32} M[r][h] * blk[h][l]
//   out[r][c] = sum_{l<32} T[r][l] * M[c][l]
__global__ __launch_bounds__(256) void k_inv(const float* __restrict__ blk,
                                             const float* __restrict__ M,
                                             const float* __restrict__ MT,
                                             float* __restrict__ out) {
    const int bo = blockIdx.x;
    const int t  = threadIdx.x;
    __shared__ float smem[8448];       // Mcs[128][33] | Ts[128][33]; reused as outS[128][65]
    float* Mcs  = smem;
    float* Ts   = smem + 4224;
    float* outS = smem;

    // stage Mcs[r][h] = M[r][h<32] * 1/16384 (coalesced 128B row chunks)
#pragma unroll
    for (int j = 0; j < 16; ++j) {
        int idx = t + j * 256;
        int r = idx >> 5, h = idx & 31;
        Mcs[r * 33 + h] = M[r * 128 + h] * (1.f / 16384.f);
    }
    __syncthreads();

    const int r  = t & 127;
    const int rh = __builtin_amdgcn_readfirstlane(t >> 7);   // 0 or 1

    // T phase: lane -> r (Mcs per-lane, conflict-free), blk rows via s_load.
    {
        const float* bp = blk + (size_t)bo * (MD * MD);
        float acc[16];
#pragma unroll
        for (int j = 0; j < 16; ++j) acc[j] = 0.f;
#pragma unroll 4
        for (int h = 0; h < MD; ++h) {
            float mc = Mcs[r * 33 + h];
            const float* brow = bp + h * MD + rh * 16;   // uniform -> s_load_x8
#pragma unroll
            for (int j = 0; j < 16; ++j)
                acc[j] = fmaf(brow[j], mc, acc[j]);
        }
#pragma unroll
        for (int j = 0; j < 16; ++j) Ts[r * 33 + rh * 16 + j] = acc[j];
    }
    __syncthreads();

    // out phase: out[r][c] = sum_l Ts[r][l] * MT[l*128 + c]; c-set (64) uniform.
    float acc[64];
#pragma unroll
    for (int j = 0; j < 64; ++j) acc[j] = 0.f;
#pragma unroll 2
    for (int l = 0; l < MD; ++l) {
        float tv = Ts[r * 33 + l];                   // per-lane, (r+l)%32 banks
        const float* mt = MT + l * 128 + rh * 64;    // uniform -> s_load_x16
#pragma unroll
        for (int j = 0; j < 64; ++j)
            acc[j] = fmaf(mt[j], tv, acc[j]);
    }

    // LDS-transpose epilogue for coalesced stores (two rounds: c-half 0, 1).
    float* op = out + (size_t)bo * (SS * SS);
    for (int rr = 0; rr < 2; ++rr) {
        __syncthreads();               // prior reads of smem done
        if (rh == rr) {
#pragma unroll
            for (int j = 0; j < 64; ++j) outS[r * 65 + j] = acc[j];
        }
        __syncthreads();
        const int cc = t & 63;
        const int r0 = t >> 6;
#pragma unroll
        for (int j = 0; j < 32; ++j) {
            int rrow = r0 + 4 * j;
            op[rrow * SS + rr * 64 + cc] = outS[rrow * 65 + cc];
        }
    }
}

extern "C" void kernel_launch(void* const* d_in, const int* in_sizes, int n_in,
                              void* d_out, int out_size, void* d_ws, size_t ws_size,
                              hipStream_t stream) {
    const float* x   = (const float*)d_in[0];
    const float* wgt = (const float*)d_in[1];
    float* outp = (float*)d_out;
    float* ws   = (float*)d_ws;

    float* M   = ws + OFF_M;
    float* MT  = ws + OFF_MT;
    float* Xh  = ws + OFF_XH;
    float* blk = ws + OFF_BLK;

    k_build<<<64, 256, 0, stream>>>(M, MT);
    k_fwd  <<<2048, 256, 0, stream>>>(x, MT, Xh);
    k_mix  <<<1024, 256, 0, stream>>>(Xh, wgt, blk);
    k_inv  <<<2048, 256, 0, stream>>>(blk, M, MT, outp);
}

// Round 3
// 169.350 us; speedup vs baseline: 1.0001x; 1.0001x over previous
//
#include <hip/hip_runtime.h>
#include <math.h>

// SpectralConv2d: out = idht2( mix( dht2(x)[:, :, :32, :32], W ) ) / S^2
// x:  [32][64][128][128] f32   weights1: [64][64][32][32] f32
// out:[32][64][128][128] f32
//
// M is the recursive pseudo-Hartley operator (NOT plain cas(2pi kn/N)):
//   M[k,n] = prod over levels (size Nj = 128,64,...,2):
//     if bit_j(n): (k_j < Nj/2 ? +1 : -1) * cas(2*pi*(k_j mod Nj/2)/Nj), else 1
//     with k_{j+1} = k_j mod (Nj/2).
//
// Pipeline: k_build -> k_fwd (Xh[bi][m]) -> t_xh (Xh_t[m][i*32+b]) ->
//           t_w (Wt[m][i*64+o]) -> k_mix3 (blk_t[m][b*64+o], wave-per-mode,
//           read-once traffic ~56MB vs 786MB L3-bound baseline) ->
//           t_blk (blk[bo][m]) -> k_inv.

#define SS   128
#define MD   32
#define NBAT 32
#define CI   64
#define CO   64

#define TWO_PI 6.2831853071795864769

// ws layout (floats). blk_t aliases Xh (dead after t_xh); blk aliases Xh_t
// (dead after k_mix3). Total ~32.1 MB.
static const size_t OFF_M    = 0;
static const size_t OFF_MT   = 16384;
static const size_t OFF_XH   = 32768;                    // 2048*1024
static const size_t OFF_XHT  = 32768 + 2097152;          // 2048*1024
static const size_t OFF_WT   = 32768 + 2 * 2097152;      // 4096*1024
static const size_t OFF_BLKT = OFF_XH;                   // alias
static const size_t OFF_BLK  = OFF_XHT;                  // alias

__global__ void k_build(float* __restrict__ M, float* __restrict__ MT) {
    int idx = blockIdx.x * 256 + threadIdx.x;   // 16384 entries
    int k = idx >> 7, n = idx & 127;
    float prod = 1.f;
    int kk = k, nn = n;
    for (int Nj = SS; Nj > 1; Nj >>= 1) {
        int half = Nj >> 1;
        int k1 = kk & (half - 1);
        if (nn & 1) {
            double ang = (TWO_PI / (double)Nj) * (double)k1;
            float cas = (float)(cos(ang) + sin(ang));
            prod *= (kk < half) ? cas : -cas;
        }
        kk = k1;
        nn >>= 1;
    }
    M[idx] = prod;
    MT[n * 128 + k] = prod;
}

// Forward: per (b,c) block: Xh[k][l] = sum_{h,w} M[k][h]*M[l][w]*x[h][w], k,l<32
__global__ __launch_bounds__(256) void k_fwd(const float* __restrict__ x,
                                             const float* __restrict__ MT,
                                             float* __restrict__ Xh) {
    const int bc = blockIdx.x;
    const float* xp = x + (size_t)bc * (SS * SS);
    const int t = threadIdx.x;
    __shared__ float Ys[MD][SS + 1];   // Y[k][w], padded: bank = (k+w)%32

    const int w  = t & 127;
    const int kh = __builtin_amdgcn_readfirstlane(t >> 7);   // 0,0,1,1 per wave
    {
        float acc[16];
#pragma unroll
        for (int j = 0; j < 16; ++j) acc[j] = 0.f;
#pragma unroll 4
        for (int h = 0; h < SS; ++h) {
            float xv = xp[h * SS + w];                  // coalesced
            const float* mrow = MT + h * 128 + kh * 16; // uniform -> s_load
#pragma unroll
            for (int j = 0; j < 16; ++j)
                acc[j] = fmaf(mrow[j], xv, acc[j]);
        }
#pragma unroll
        for (int j = 0; j < 16; ++j) Ys[kh * 16 + j][w] = acc[j];
    }
    __syncthreads();

    const int k   = t & 31;
    const int dup = (t >> 5) & 1;
    const int wid = __builtin_amdgcn_readfirstlane(t >> 6);  // 0..3
    float z[8];
#pragma unroll
    for (int j = 0; j < 8; ++j) z[j] = 0.f;
#pragma unroll 8
    for (int ww = 0; ww < SS; ++ww) {
        float yv = Ys[k][ww];                        // conflict-free
        const float* mcol = MT + ww * 128 + wid * 8; // uniform -> s_load
#pragma unroll
        for (int j = 0; j < 8; ++j)
            z[j] = fmaf(mcol[j], yv, z[j]);
    }
    if (dup == 0) {
        float* outp = Xh + (size_t)bc * (MD * MD) + k * MD + wid * 8;
#pragma unroll
        for (int j = 0; j < 8; ++j) outp[j] = z[j];
    }
}

// Transpose Xh[(b*64+i)][m] -> Xh_t[m][i*32+b].  2048 blocks: (i, m-tile).
__global__ __launch_bounds__(256) void t_xh(const float* __restrict__ Xh,
                                            float* __restrict__ Xh_t) {
    __shared__ float tile[32][33];
    const int i  = blockIdx.x & 63;
    const int mt = blockIdx.x >> 6;      // 0..31
    const int tx = threadIdx.x & 31;
    const int ty = threadIdx.x >> 5;     // 0..7
#pragma unroll
    for (int j = 0; j < 4; ++j) {
        int b = ty + 8 * j;
        tile[b][tx] = Xh[(b * 64 + i) * 1024 + mt * 32 + tx];
    }
    __syncthreads();
#pragma unroll
    for (int j = 0; j < 4; ++j) {
        int row = ty + 8 * j;
        Xh_t[(mt * 32 + row) * 2048 + i * 32 + tx] = tile[tx][row];
    }
}

// Transpose wgt[(i*64+o)][m] -> Wt[m][i*64+o].  4096 blocks: (io-tile, m-tile).
__global__ __launch_bounds__(256) void t_w(const float* __restrict__ wgt,
                                           float* __restrict__ Wt) {
    __shared__ float tile[32][33];
    const int mt  = blockIdx.x & 31;
    const int iot = blockIdx.x >> 5;     // 0..127
    const int tx = threadIdx.x & 31;
    const int ty = threadIdx.x >> 5;
#pragma unroll
    for (int j = 0; j < 4; ++j) {
        int r = ty + 8 * j;
        tile[r][tx] = wgt[(iot * 32 + r) * 1024 + mt * 32 + tx];
    }
    __syncthreads();
#pragma unroll
    for (int j = 0; j < 4; ++j) {
        int r = ty + 8 * j;
        Wt[(mt * 32 + r) * 4096 + iot * 32 + tx] = tile[tx][r];
    }
}

// Mix, wave-per-mode: blk_t[m][b*64+o] = sum_i Xh_t[m][i*32+b]*We + Xh_t[nm][i*32+b]*Wo
// We = 0.5*(Wt[m][io]+Wt[nm][io]), Wo = 0.5*(Wt[m][io]-Wt[nm][io]).
// lane = o (coalesced w rows); x values wave-uniform -> s_load; each operand
// read at most twice total => ~56MB L3 traffic (was 786MB).
__global__ __launch_bounds__(64) void k_mix3(const float* __restrict__ Xh_t,
                                             const float* __restrict__ Wt,
                                             float* __restrict__ blk_t) {
    const int m  = blockIdx.x;           // 0..1023
    const int o  = threadIdx.x;          // 0..63
    const int xm = m >> 5, ym = m & 31;
    const int nm = (((32 - xm) & 31) << 5) | ((32 - ym) & 31);

    const float* wp  = Wt + m * 4096 + o;
    const float* wpn = Wt + nm * 4096 + o;
    const float* xp  = Xh_t + m * 2048;    // uniform
    const float* xpn = Xh_t + nm * 2048;   // uniform

    float acc[32];
#pragma unroll
    for (int b = 0; b < 32; ++b) acc[b] = 0.f;

#pragma unroll 2
    for (int i = 0; i < 64; ++i) {
        float wm = wp[i * 64];
        float wn = wpn[i * 64];
        float we = 0.5f * (wm + wn);
        float wo = 0.5f * (wm - wn);
#pragma unroll
        for (int b = 0; b < 32; ++b) {
            float x1  = xp[i * 32 + b];    // uniform -> s_load
            float x1n = xpn[i * 32 + b];   // uniform -> s_load
            acc[b] = fmaf(x1, we, fmaf(x1n, wo, acc[b]));
        }
    }

    float* op = blk_t + m * 2048 + o;
#pragma unroll
    for (int b = 0; b < 32; ++b) op[b * 64] = acc[b];   // coalesced 256B rows
}

// Transpose blk_t[m][bo] -> blk[bo][m].  2048 blocks: (bo-tile, m-tile).
__global__ __launch_bounds__(256) void t_blk(const float* __restrict__ blk_t,
                                             float* __restrict__ blk) {
    __shared__ float tile[32][33];
    const int mt  = blockIdx.x & 31;
    const int bot = blockIdx.x >> 5;     // 0..63
    const int tx = threadIdx.x & 31;
    const int ty = threadIdx.x >> 5;
#pragma unroll
    for (int j = 0; j < 4; ++j) {
        int r = ty + 8 * j;
        tile[r][tx] = blk_t[(mt * 32 + r) * 2048 + bot * 32 + tx];
    }
    __syncthreads();
#pragma unroll
    for (int j = 0; j < 4; ++j) {
        int r = ty + 8 * j;
        blk[(bot * 32 + r) * 1024 + mt * 32 + tx] = tile[tx][r];
    }
}

// Inverse: per (b,o) block:
//   T[r][l]   = (1/16384) * sum_{h<32} M[r][h] * blk[h][l]
//   out[r][c] = sum_{l<32} T[r][l] * M[c][l]
__global__ __launch_bounds__(256) void k_inv(const float* __restrict__ blk,
                                             const float* __restrict__ M,
                                             const float* __restrict__ MT,
                                             float* __restrict__ out) {
    const int bo = blockIdx.x;
    const int t  = threadIdx.x;
    __shared__ float smem[8448];       // Mcs[128][33] | Ts[128][33]; reused as outS[128][65]
    float* Mcs  = smem;
    float* Ts   = smem + 4224;
    float* outS = smem;

#pragma unroll
    for (int j = 0; j < 16; ++j) {
        int idx = t + j * 256;
        int r = idx >> 5, h = idx & 31;
        Mcs[r * 33 + h] = M[r * 128 + h] * (1.f / 16384.f);
    }
    __syncthreads();

    const int r  = t & 127;
    const int rh = __builtin_amdgcn_readfirstlane(t >> 7);   // 0 or 1

    {
        const float* bp = blk + (size_t)bo * (MD * MD);
        float acc[16];
#pragma unroll
        for (int j = 0; j < 16; ++j) acc[j] = 0.f;
#pragma unroll 4
        for (int h = 0; h < MD; ++h) {
            float mc = Mcs[r * 33 + h];
            const float* brow = bp + h * MD + rh * 16;   // uniform -> s_load_x8
#pragma unroll
            for (int j = 0; j < 16; ++j)
                acc[j] = fmaf(brow[j], mc, acc[j]);
        }
#pragma unroll
        for (int j = 0; j < 16; ++j) Ts[r * 33 + rh * 16 + j] = acc[j];
    }
    __syncthreads();

    float acc[64];
#pragma unroll
    for (int j = 0; j < 64; ++j) acc[j] = 0.f;
#pragma unroll 2
    for (int l = 0; l < MD; ++l) {
        float tv = Ts[r * 33 + l];                   // per-lane, conflict-free
        const float* mt = MT + l * 128 + rh * 64;    // uniform -> s_load_x16
#pragma unroll
        for (int j = 0; j < 64; ++j)
            acc[j] = fmaf(mt[j], tv, acc[j]);
    }

    float* op = out + (size_t)bo * (SS * SS);
    for (int rr = 0; rr < 2; ++rr) {
        __syncthreads();
        if (rh == rr) {
#pragma unroll
            for (int j = 0; j < 64; ++j) outS[r * 65 + j] = acc[j];
        }
        __syncthreads();
        const int cc = t & 63;
        const int r0 = t >> 6;
#pragma unroll
        for (int j = 0; j < 32; ++j) {
            int rrow = r0 + 4 * j;
            op[rrow * SS + rr * 64 + cc] = outS[rrow * 65 + cc];
        }
    }
}

extern "C" void kernel_launch(void* const* d_in, const int* in_sizes, int n_in,
                              void* d_out, int out_size, void* d_ws, size_t ws_size,
                              hipStream_t stream) {
    const float* x   = (const float*)d_in[0];
    const float* wgt = (const float*)d_in[1];
    float* outp = (float*)d_out;
    float* ws   = (float*)d_ws;

    float* M     = ws + OFF_M;
    float* MT    = ws + OFF_MT;
    float* Xh    = ws + OFF_XH;
    float* Xh_t  = ws + OFF_XHT;
    float* Wt    = ws + OFF_WT;
    float* blk_t = ws + OFF_BLKT;   // aliases Xh (dead after t_xh)
    float* blk   = ws + OFF_BLK;    // aliases Xh_t (dead after k_mix3)

    k_build<<<64, 256, 0, stream>>>(M, MT);
    k_fwd  <<<2048, 256, 0, stream>>>(x, MT, Xh);
    t_xh   <<<2048, 256, 0, stream>>>(Xh, Xh_t);
    t_w    <<<4096, 256, 0, stream>>>(wgt, Wt);
    k_mix3 <<<1024, 64, 0, stream>>>(Xh_t, Wt, blk_t);
    t_blk  <<<2048, 256, 0, stream>>>(blk_t, blk);
    k_inv  <<<2048, 256, 0, stream>>>(blk, M, MT, outp);
}

// Round 4
// 145.692 us; speedup vs baseline: 1.1625x; 1.1624x over previous
//
#include <hip/hip_runtime.h>
#include <math.h>

// SpectralConv2d: out = idht2( mix( dht2(x)[:, :, :32, :32], W ) ) / S^2
// x:  [32][64][128][128] f32   weights1: [64][64][32][32] f32
// out:[32][64][128][128] f32
//
// M is the recursive pseudo-Hartley operator (NOT plain cas(2pi kn/N)):
//   M[k,n] = prod over levels (size Nj = 128,64,...,2):
//     if bit_j(n): (k_j < Nj/2 ? +1 : -1) * cas(2*pi*(k_j mod Nj/2)/Nj), else 1
//     with k_{j+1} = k_j mod (Nj/2).
//
// Pipeline: k_build -> k_fwd (Xh[bi][m]) -> t_xh (Xh_t[m][i*32+b]) ->
//           t_w (Wt[m][i*64+o]) -> k_mix4 (pair-block, LDS-staged X,
//           computes modes m and nm together) -> t_blk (blk[bo][m]) -> k_inv.

#define SS   128
#define MD   32
#define NBAT 32
#define CI   64
#define CO   64

#define TWO_PI 6.2831853071795864769

// ws layout (floats). blk_t aliases Xh (dead after t_xh); blk aliases Xh_t
// (dead after k_mix4). Total ~32.1 MB.
static const size_t OFF_M    = 0;
static const size_t OFF_MT   = 16384;
static const size_t OFF_XH   = 32768;                    // 2048*1024
static const size_t OFF_XHT  = 32768 + 2097152;          // 2048*1024
static const size_t OFF_WT   = 32768 + 2 * 2097152;      // 4096*1024
static const size_t OFF_BLKT = OFF_XH;                   // alias
static const size_t OFF_BLK  = OFF_XHT;                  // alias

__global__ void k_build(float* __restrict__ M, float* __restrict__ MT) {
    int idx = blockIdx.x * 256 + threadIdx.x;   // 16384 entries
    int k = idx >> 7, n = idx & 127;
    float prod = 1.f;
    int kk = k, nn = n;
    for (int Nj = SS; Nj > 1; Nj >>= 1) {
        int half = Nj >> 1;
        int k1 = kk & (half - 1);
        if (nn & 1) {
            double ang = (TWO_PI / (double)Nj) * (double)k1;
            float cas = (float)(cos(ang) + sin(ang));
            prod *= (kk < half) ? cas : -cas;
        }
        kk = k1;
        nn >>= 1;
    }
    M[idx] = prod;
    MT[n * 128 + k] = prod;
}

// Forward: per (b,c) block: Xh[k][l] = sum_{h,w} M[k][h]*M[l][w]*x[h][w], k,l<32
__global__ __launch_bounds__(256) void k_fwd(const float* __restrict__ x,
                                             const float* __restrict__ MT,
                                             float* __restrict__ Xh) {
    const int bc = blockIdx.x;
    const float* xp = x + (size_t)bc * (SS * SS);
    const int t = threadIdx.x;
    __shared__ float Ys[MD][SS + 1];   // Y[k][w], padded: bank = (k+w)%32

    const int w  = t & 127;
    const int kh = __builtin_amdgcn_readfirstlane(t >> 7);   // 0,0,1,1 per wave
    {
        float acc[16];
#pragma unroll
        for (int j = 0; j < 16; ++j) acc[j] = 0.f;
#pragma unroll 4
        for (int h = 0; h < SS; ++h) {
            float xv = xp[h * SS + w];                  // coalesced
            const float* mrow = MT + h * 128 + kh * 16; // uniform -> s_load
#pragma unroll
            for (int j = 0; j < 16; ++j)
                acc[j] = fmaf(mrow[j], xv, acc[j]);
        }
#pragma unroll
        for (int j = 0; j < 16; ++j) Ys[kh * 16 + j][w] = acc[j];
    }
    __syncthreads();

    const int k   = t & 31;
    const int dup = (t >> 5) & 1;
    const int wid = __builtin_amdgcn_readfirstlane(t >> 6);  // 0..3
    float z[8];
#pragma unroll
    for (int j = 0; j < 8; ++j) z[j] = 0.f;
#pragma unroll 8
    for (int ww = 0; ww < SS; ++ww) {
        float yv = Ys[k][ww];                        // conflict-free
        const float* mcol = MT + ww * 128 + wid * 8; // uniform -> s_load
#pragma unroll
        for (int j = 0; j < 8; ++j)
            z[j] = fmaf(mcol[j], yv, z[j]);
    }
    if (dup == 0) {
        float* outp = Xh + (size_t)bc * (MD * MD) + k * MD + wid * 8;
#pragma unroll
        for (int j = 0; j < 8; ++j) outp[j] = z[j];
    }
}

// Transpose Xh[(b*64+i)][m] -> Xh_t[m][i*32+b].  2048 blocks: (i, m-tile).
__global__ __launch_bounds__(256) void t_xh(const float* __restrict__ Xh,
                                            float* __restrict__ Xh_t) {
    __shared__ float tile[32][33];
    const int i  = blockIdx.x & 63;
    const int mt = blockIdx.x >> 6;      // 0..31
    const int tx = threadIdx.x & 31;
    const int ty = threadIdx.x >> 5;     // 0..7
#pragma unroll
    for (int j = 0; j < 4; ++j) {
        int b = ty + 8 * j;
        tile[b][tx] = Xh[(b * 64 + i) * 1024 + mt * 32 + tx];
    }
    __syncthreads();
#pragma unroll
    for (int j = 0; j < 4; ++j) {
        int row = ty + 8 * j;
        Xh_t[(mt * 32 + row) * 2048 + i * 32 + tx] = tile[tx][row];
    }
}

// Transpose wgt[(i*64+o)][m] -> Wt[m][i*64+o].  4096 blocks: (io-tile, m-tile).
__global__ __launch_bounds__(256) void t_w(const float* __restrict__ wgt,
                                           float* __restrict__ Wt) {
    __shared__ float tile[32][33];
    const int mt  = blockIdx.x & 31;
    const int iot = blockIdx.x >> 5;     // 0..127
    const int tx = threadIdx.x & 31;
    const int ty = threadIdx.x >> 5;
#pragma unroll
    for (int j = 0; j < 4; ++j) {
        int r = ty + 8 * j;
        tile[r][tx] = wgt[(iot * 32 + r) * 1024 + mt * 32 + tx];
    }
    __syncthreads();
#pragma unroll
    for (int j = 0; j < 4; ++j) {
        int r = ty + 8 * j;
        Wt[(mt * 32 + r) * 4096 + iot * 32 + tx] = tile[tx][r];
    }
}

// Mix, pair-block: block = mode-pair (m, nm). Outputs BOTH modes:
//   out[m]  = x1*We + x1n*Wo,  out[nm] = x1n*We - x1*Wo
//   (We = 0.5*(w[m]+w[nm]), Wo = 0.5*(w[m]-w[nm]))
// X[m], X[nm] staged in LDS (parallel float4 loads, latency overlapped);
// weights per-lane coalesced 256B rows (L1-shared across the 4 waves);
// thread = (o = t&63, bq = t>>6) computes 8 b for both modes.
// Blocks with m > nm retire immediately; self-paired modes (wo==0) are
// handled by the same code path (writes same value twice).
__global__ __launch_bounds__(256) void k_mix4(const float* __restrict__ Xh_t,
                                              const float* __restrict__ Wt,
                                              float* __restrict__ blk_t) {
    const int m  = blockIdx.x;           // 0..1023
    const int xm = m >> 5, ym = m & 31;
    const int nm = (((32 - xm) & 31) << 5) | ((32 - ym) & 31);
    if (m > nm) return;
    const int t = threadIdx.x;

    __shared__ float Xs[2][64][32];      // [mode][i][b], 16 KB

    {   // stage both mode rows (2048 floats each) as float4
        const float4* xm4 = (const float4*)(Xh_t + m * 2048);
        const float4* xn4 = (const float4*)(Xh_t + nm * 2048);
        float4* s0 = (float4*)&Xs[0][0][0];
        float4* s1 = (float4*)&Xs[1][0][0];
        s0[t]       = xm4[t];
        s0[t + 256] = xm4[t + 256];
        s1[t]       = xn4[t];
        s1[t + 256] = xn4[t + 256];
    }
    __syncthreads();

    const int o  = t & 63;
    const int bq = t >> 6;               // wave-uniform b-octet
    const float* wpm = Wt + m * 4096 + o;
    const float* wpn = Wt + nm * 4096 + o;

    float am[8], an[8];
#pragma unroll
    for (int j = 0; j < 8; ++j) { am[j] = 0.f; an[j] = 0.f; }

#pragma unroll 4
    for (int i = 0; i < 64; ++i) {
        float wm = wpm[i * 64];          // coalesced 256B, L1 hit across waves
        float wn = wpn[i * 64];
        float we = 0.5f * (wm + wn);
        float wo = 0.5f * (wm - wn);
        const float* xr  = &Xs[0][i][bq * 8];   // wave-uniform -> b128 broadcast
        const float* xrn = &Xs[1][i][bq * 8];
#pragma unroll
        for (int j = 0; j < 8; ++j) {
            float x1  = xr[j];
            float x1n = xrn[j];
            am[j] = fmaf(x1, we, fmaf(x1n, wo, am[j]));
            an[j] = fmaf(x1n, we, fmaf(x1, -wo, an[j]));
        }
    }

    float* om = blk_t + m * 2048 + o;
    float* on = blk_t + nm * 2048 + o;
#pragma unroll
    for (int j = 0; j < 8; ++j) {
        int b = bq * 8 + j;
        om[b * 64] = am[j];              // coalesced 256B rows
        on[b * 64] = an[j];
    }
}

// Transpose blk_t[m][bo] -> blk[bo][m].  2048 blocks: (bo-tile, m-tile).
__global__ __launch_bounds__(256) void t_blk(const float* __restrict__ blk_t,
                                             float* __restrict__ blk) {
    __shared__ float tile[32][33];
    const int mt  = blockIdx.x & 31;
    const int bot = blockIdx.x >> 5;     // 0..63
    const int tx = threadIdx.x & 31;
    const int ty = threadIdx.x >> 5;
#pragma unroll
    for (int j = 0; j < 4; ++j) {
        int r = ty + 8 * j;
        tile[r][tx] = blk_t[(mt * 32 + r) * 2048 + bot * 32 + tx];
    }
    __syncthreads();
#pragma unroll
    for (int j = 0; j < 4; ++j) {
        int r = ty + 8 * j;
        blk[(bot * 32 + r) * 1024 + mt * 32 + tx] = tile[tx][r];
    }
}

// Inverse: per (b,o) block:
//   T[r][l]   = (1/16384) * sum_{h<32} M[r][h] * blk[h][l]
//   out[r][c] = sum_{l<32} T[r][l] * M[c][l]
__global__ __launch_bounds__(256) void k_inv(const float* __restrict__ blk,
                                             const float* __restrict__ M,
                                             const float* __restrict__ MT,
                                             float* __restrict__ out) {
    const int bo = blockIdx.x;
    const int t  = threadIdx.x;
    __shared__ float smem[8448];       // Mcs[128][33] | Ts[128][33]; reused as outS[128][65]
    float* Mcs  = smem;
    float* Ts   = smem + 4224;
    float* outS = smem;

#pragma unroll
    for (int j = 0; j < 16; ++j) {
        int idx = t + j * 256;
        int r = idx >> 5, h = idx & 31;
        Mcs[r * 33 + h] = M[r * 128 + h] * (1.f / 16384.f);
    }
    __syncthreads();

    const int r  = t & 127;
    const int rh = __builtin_amdgcn_readfirstlane(t >> 7);   // 0 or 1

    {
        const float* bp = blk + (size_t)bo * (MD * MD);
        float acc[16];
#pragma unroll
        for (int j = 0; j < 16; ++j) acc[j] = 0.f;
#pragma unroll 4
        for (int h = 0; h < MD; ++h) {
            float mc = Mcs[r * 33 + h];
            const float* brow = bp + h * MD + rh * 16;   // uniform -> s_load_x8
#pragma unroll
            for (int j = 0; j < 16; ++j)
                acc[j] = fmaf(brow[j], mc, acc[j]);
        }
#pragma unroll
        for (int j = 0; j < 16; ++j) Ts[r * 33 + rh * 16 + j] = acc[j];
    }
    __syncthreads();

    float acc[64];
#pragma unroll
    for (int j = 0; j < 64; ++j) acc[j] = 0.f;
#pragma unroll 2
    for (int l = 0; l < MD; ++l) {
        float tv = Ts[r * 33 + l];                   // per-lane, conflict-free
        const float* mt = MT + l * 128 + rh * 64;    // uniform -> s_load_x16
#pragma unroll
        for (int j = 0; j < 64; ++j)
            acc[j] = fmaf(mt[j], tv, acc[j]);
    }

    float* op = out + (size_t)bo * (SS * SS);
    for (int rr = 0; rr < 2; ++rr) {
        __syncthreads();
        if (rh == rr) {
#pragma unroll
            for (int j = 0; j < 64; ++j) outS[r * 65 + j] = acc[j];
        }
        __syncthreads();
        const int cc = t & 63;
        const int r0 = t >> 6;
#pragma unroll
        for (int j = 0; j < 32; ++j) {
            int rrow = r0 + 4 * j;
            op[rrow * SS + rr * 64 + cc] = outS[rrow * 65 + cc];
        }
    }
}

extern "C" void kernel_launch(void* const* d_in, const int* in_sizes, int n_in,
                              void* d_out, int out_size, void* d_ws, size_t ws_size,
                              hipStream_t stream) {
    const float* x   = (const float*)d_in[0];
    const float* wgt = (const float*)d_in[1];
    float* outp = (float*)d_out;
    float* ws   = (float*)d_ws;

    float* M     = ws + OFF_M;
    float* MT    = ws + OFF_MT;
    float* Xh    = ws + OFF_XH;
    float* Xh_t  = ws + OFF_XHT;
    float* Wt    = ws + OFF_WT;
    float* blk_t = ws + OFF_BLKT;   // aliases Xh (dead after t_xh)
    float* blk   = ws + OFF_BLK;    // aliases Xh_t (dead after k_mix4)

    k_build<<<64, 256, 0, stream>>>(M, MT);
    k_fwd  <<<2048, 256, 0, stream>>>(x, MT, Xh);
    t_xh   <<<2048, 256, 0, stream>>>(Xh, Xh_t);
    t_w    <<<4096, 256, 0, stream>>>(wgt, Wt);
    k_mix4 <<<1024, 256, 0, stream>>>(Xh_t, Wt, blk_t);
    t_blk  <<<2048, 256, 0, stream>>>(blk_t, blk);
    k_inv  <<<2048, 256, 0, stream>>>(blk, M, MT, outp);
}